// Round 2
// baseline (183.448 us; speedup 1.0000x reference)
//
#include <hip/hip_runtime.h>
#include <hip/hip_bf16.h>

#define B_SZ 2
#define SEQ 2048
#define DMODEL 128
#define DINNER 1024
#define NHEADS 8
#define HEADDIM 128
#define DSTATE 128
#define CONVDIM 1280
#define NPROJ 2304       /* z (1024) + xBC (1280) — GEMM part of in_proj */
#define NTOK (B_SZ*SEQ)  /* 4096 */
#define CHUNK 64
#define NCHUNK (SEQ/CHUNK) /* 32 */
#define LDT 72           /* padded t-stride for LDS tiles (16B-aligned rows) */
#define LDU 76           /* conv staging stride: 152B rows, 8B-aligned, conflict-free writes */

using bf16_t = __hip_bfloat16;
using short8 = __attribute__((ext_vector_type(8))) short;
using short4v= __attribute__((ext_vector_type(4))) short;
using f32x4  = __attribute__((ext_vector_type(4))) float;

__device__ __forceinline__ float silu_f(float x) { return x / (1.f + expf(-x)); }
__device__ __forceinline__ float bf2f(short s) {
    unsigned u = ((unsigned)(unsigned short)s) << 16;
    return __uint_as_float(u);
}
__device__ __forceinline__ short f2bf_s(float f) {
    bf16_t h = __float2bfloat16(f);
    return *(short*)&h;
}

// ---- fused: weight casts (blocks >= NTOK, x4 vectorized) + LN1 + dt/softplus head ----
__global__ __launch_bounds__(128) void head_fused(
        const float* __restrict__ hidden,
        const float* __restrict__ ln1_w, const float* __restrict__ ln1_b,
        const float* __restrict__ w_in,
        const float* __restrict__ dt_bias, const float* __restrict__ A_log,
        bf16_t* __restrict__ h_bf, float* __restrict__ dtb, float* __restrict__ ldAb,
        const float* __restrict__ wa, int na, const float* __restrict__ wb, int nb,
        const float* __restrict__ wc, int nc,
        bf16_t* __restrict__ oa, bf16_t* __restrict__ ob, bf16_t* __restrict__ oc) {
    int blk = blockIdx.x;
    if (blk >= NTOK) {
        int i = ((blk - NTOK) * 128 + threadIdx.x) * 4;   // na,nb,nc all %4==0
        const float* src; bf16_t* dst; int base;
        if (i < na)            { src = wa; dst = oa; base = 0; }
        else if (i < na + nb)  { src = wb; dst = ob; base = na; }
        else if (i < na+nb+nc) { src = wc; dst = oc; base = na + nb; }
        else return;
        int k = i - base;
        f32x4 v = *(const f32x4*)(src + k);
        short4v o;
#pragma unroll
        for (int r = 0; r < 4; r++) o[r] = f2bf_s(v[r]);
        *(short4v*)(dst + k) = o;
        return;
    }
    int m = blk, t = threadIdx.x;
    int wave = t >> 6, lane = t & 63;
    __shared__ float sA[2], sB[2];
    __shared__ float sred[2][8];
    float v = hidden[(size_t)m*DMODEL + t];
    float s = v;
#pragma unroll
    for (int d = 1; d < 64; d <<= 1) s += __shfl_xor(s, d, 64);
    if (lane == 0) sA[wave] = s;
    __syncthreads();
    float mean = (sA[0] + sA[1]) * (1.f/128.f);
    float xc = v - mean;
    float q = xc * xc;
#pragma unroll
    for (int d = 1; d < 64; d <<= 1) q += __shfl_xor(q, d, 64);
    if (lane == 0) sB[wave] = q;
    __syncthreads();
    float var = (sB[0] + sB[1]) * (1.f/128.f);
    float o = xc * rsqrtf(var + 1e-5f) * ln1_w[t] + ln1_b[t];
    h_bf[(size_t)m*DMODEL + t] = __float2bfloat16(o);
#pragma unroll
    for (int hd = 0; hd < NHEADS; hd++) {
        float p = o * w_in[(size_t)(NPROJ + hd)*DMODEL + t];
#pragma unroll
        for (int d = 1; d < 64; d <<= 1) p += __shfl_xor(p, d, 64);
        if (lane == 0) sred[wave][hd] = p;
    }
    __syncthreads();
    if (t < NHEADS) {
        float ssum = sred[0][t] + sred[1][t] + dt_bias[t];
        float dtv = (ssum > 20.f) ? ssum : log1pf(expf(ssum));
        float Av = -expf(A_log[t]);
        dtb[m*NHEADS + t] = dtv;
        ldAb[m*NHEADS + t] = dtv * Av;
    }
}

// ---- in_proj GEMM with fused depthwise conv+silu on the xBC columns ----
// grid (64, 36): by<16 -> z columns (plain GEMM -> zbuf); by>=16 -> xBC columns,
// computed with a 16-row halo into LDS, conv(k=4)+bias+silu applied, written to xBCb.
__global__ __launch_bounds__(256) void gemm_conv(const bf16_t* __restrict__ A,
                                                 const bf16_t* __restrict__ W,
                                                 const float* __restrict__ conv_w,
                                                 const float* __restrict__ conv_b,
                                                 bf16_t* __restrict__ zbuf,
                                                 bf16_t* __restrict__ xBCb) {
    int bx = blockIdx.x, by = blockIdx.y;
    int t = threadIdx.x, wave = t >> 6, lane = t & 63;
    int lr = lane & 15, quad = lane >> 4;
    int m0 = bx * 64;
    if (by < 16) {
        int n0 = by * 64;
        int mw = m0 + wave * 16;
        f32x4 acc[4];
#pragma unroll
        for (int j = 0; j < 4; j++) acc[j] = (f32x4){0.f,0.f,0.f,0.f};
#pragma unroll
        for (int k0 = 0; k0 < 128; k0 += 32) {
            short8 a = *(const short8*)(A + (size_t)(mw + lr)*DMODEL + k0 + quad*8);
#pragma unroll
            for (int j = 0; j < 4; j++) {
                short8 b = *(const short8*)(W + (size_t)(n0 + j*16 + lr)*DMODEL + k0 + quad*8);
                acc[j] = __builtin_amdgcn_mfma_f32_16x16x32_bf16(a, b, acc[j], 0, 0, 0);
            }
        }
#pragma unroll
        for (int j = 0; j < 4; j++)
#pragma unroll
            for (int r = 0; r < 4; r++)
                zbuf[(size_t)(mw + quad*4 + r)*DINNER + n0 + j*16 + lr] = __float2bfloat16(acc[j][r]);
        return;
    }
    // ---- xBC branch ----
    int cb0 = (by - 16) * 64;
    __shared__ bf16_t U[80*LDU];     // pre-activation, tokens m0-16..m0+63
    bool seqstart = ((bx & 31) == 0);
#pragma unroll
    for (int mt = 0; mt < 5; mt++) {
        if (mt == 0 && seqstart) continue;   // halo rows unused at sequence start
        int rb = m0 - 16 + mt*16;
        f32x4 acc = (f32x4){0.f,0.f,0.f,0.f};
#pragma unroll
        for (int k0 = 0; k0 < 128; k0 += 32) {
            short8 a = *(const short8*)(A + (size_t)(rb + lr)*DMODEL + k0 + quad*8);
            short8 b = *(const short8*)(W + (size_t)(DINNER + cb0 + wave*16 + lr)*DMODEL + k0 + quad*8);
            acc = __builtin_amdgcn_mfma_f32_16x16x32_bf16(a, b, acc, 0, 0, 0);
        }
#pragma unroll
        for (int r = 0; r < 4; r++)
            U[(mt*16 + quad*4 + r)*LDU + wave*16 + lr] = __float2bfloat16(acc[r]);
    }
    __syncthreads();
    int c4 = (t & 15) * 4;
    int tl0 = (t >> 4) * 4;
    float bias[4]; f32x4 wv[4];
#pragma unroll
    for (int j = 0; j < 4; j++) {
        bias[j] = conv_b[cb0 + c4 + j];
        wv[j] = *(const f32x4*)(conv_w + (cb0 + c4 + j)*4);
    }
    int lbase = m0 & (SEQ - 1);
#pragma unroll
    for (int it = 0; it < 4; it++) {
        int tl = tl0 + it;
        int l = lbase + tl;
        float accv[4] = {bias[0], bias[1], bias[2], bias[3]};
#pragma unroll
        for (int k = 0; k < 4; k++) {
            int ll = l - 3 + k;
            if (ll >= 0) {
                short4v u = *(const short4v*)&U[(13 + tl + k)*LDU + c4];
#pragma unroll
                for (int j = 0; j < 4; j++) accv[j] += bf2f(u[j]) * wv[j][k];
            }
        }
        short4v res;
#pragma unroll
        for (int j = 0; j < 4; j++) res[j] = f2bf_s(silu_f(accv[j]));
        *(short4v*)(xBCb + (size_t)(m0 + tl)*CONVDIM + cb0 + c4) = res;
    }
}

// ---- scan phase A (MFMA): chunk-local states; split over n-halves (1024 blocks) ----
__global__ __launch_bounds__(256) void scanA_mfma(const bf16_t* __restrict__ xBCb,
                                                  const float* __restrict__ dt,
                                                  const float* __restrict__ ldA,
                                                  bf16_t* __restrict__ Sloc,
                                                  float* __restrict__ Pbuf) {
    int bid = blockIdx.x;
    int nh = bid & 1, c = (bid >> 1) & 31, hd = (bid >> 6) & 7, b = bid >> 9;
    int t = threadIdx.x, wave = t >> 6, lane = t & 63;
    int lr = lane & 15, quad = lane >> 4;
    __shared__ bf16_t XT[128*LDT];   // [p][t], pre-scaled by w_t
    __shared__ bf16_t BT[64*LDT];    // [n-half][t]
    __shared__ float ws[CHUNK];
    int m0tok = b*SEQ + c*CHUNK;
    int bhc = (b*NHEADS + hd)*NCHUNK + c;
    if (t < 64) {
        float L = ldA[(m0tok + t)*NHEADS + hd];
#pragma unroll
        for (int d = 1; d < 64; d <<= 1) {
            float u = __shfl_up(L, d, 64);
            if (lane >= d) L += u;
        }
        float Ltot = __shfl(L, 63, 64);
        ws[t] = expf(Ltot - L) * dt[(m0tok + t)*NHEADS + hd];
        if (t == 63 && nh == 0) Pbuf[bhc] = expf(Ltot);
    }
    __syncthreads();
    int tt = t & 63;
#pragma unroll
    for (int i = 0; i < 4; i++) {
        int pg = i*4 + (t >> 6);
        short8 xv = *(const short8*)(xBCb + (size_t)(m0tok + tt)*CONVDIM + hd*HEADDIM + pg*8);
        float w = ws[tt];
#pragma unroll
        for (int j = 0; j < 8; j++)
            XT[(pg*8 + j)*LDT + tt] = __float2bfloat16(bf2f(xv[j]) * w);
    }
#pragma unroll
    for (int i = 0; i < 2; i++) {
        int pg = i*4 + (t >> 6);
        short8 bv = *(const short8*)(xBCb + (size_t)(m0tok + tt)*CONVDIM + DINNER + nh*64 + pg*8);
#pragma unroll
        for (int j = 0; j < 8; j++) {
            short sv = bv[j];
            BT[(pg*8 + j)*LDT + tt] = *(bf16_t*)&sv;
        }
    }
    __syncthreads();
    int m0w = wave * 32;
    f32x4 acc[2][4];
#pragma unroll
    for (int mi = 0; mi < 2; mi++)
#pragma unroll
        for (int ni = 0; ni < 4; ni++) acc[mi][ni] = (f32x4){0.f,0.f,0.f,0.f};
#pragma unroll
    for (int k0 = 0; k0 < 64; k0 += 32) {
        short8 a[2];
#pragma unroll
        for (int mi = 0; mi < 2; mi++)
            a[mi] = *(const short8*)&XT[(m0w + mi*16 + lr)*LDT + k0 + quad*8];
#pragma unroll
        for (int ni = 0; ni < 4; ni++) {
            short8 bb = *(const short8*)&BT[(ni*16 + lr)*LDT + k0 + quad*8];
#pragma unroll
            for (int mi = 0; mi < 2; mi++)
                acc[mi][ni] = __builtin_amdgcn_mfma_f32_16x16x32_bf16(a[mi], bb, acc[mi][ni], 0, 0, 0);
        }
    }
    bf16_t* outp = Sloc + (size_t)bhc * 16384;
#pragma unroll
    for (int mi = 0; mi < 2; mi++)
#pragma unroll
        for (int ni = 0; ni < 4; ni++)
#pragma unroll
            for (int r = 0; r < 4; r++) {
                int p = m0w + mi*16 + quad*4 + r;
                int n = nh*64 + ni*16 + lr;
                outp[p*128 + n] = __float2bfloat16(acc[mi][ni][r]);
            }
}

// ---------------- scan phase B: inter-chunk recurrence, out-of-place, 512-way ----------------
__global__ __launch_bounds__(256) void scanB(const bf16_t* __restrict__ Sloc,
                                             bf16_t* __restrict__ Sini,
                                             const float* __restrict__ Pbuf) {
    int bid = blockIdx.x;                   // 512 = 16 bh * 32 slices
    int bh = bid >> 5, slice = bid & 31;
    int t = threadIdx.x;
    int off = slice*512 + t*2;
    size_t base = (size_t)bh * NCHUNK * 16384;
    float run0 = 0.f, run1 = 0.f;
    for (int cc = 0; cc < NCHUNK; cc++) {
        unsigned raw = *(const unsigned*)(Sloc + base + (size_t)cc*16384 + off);
        float P = Pbuf[bh*NCHUNK + cc];
        unsigned o0 = (unsigned)(unsigned short)f2bf_s(run0);
        unsigned o1 = (unsigned)(unsigned short)f2bf_s(run1);
        *(unsigned*)(Sini + base + (size_t)cc*16384 + off) = o0 | (o1 << 16);
        run0 = run0*P + bf2f((short)(raw & 0xffff));
        run1 = run1*P + bf2f((short)(raw >> 16));
    }
}

// ---- scan phase C (MFMA): Y = diag(e^L) C S_init^T + M X + D x; split over p-halves ----
__global__ __launch_bounds__(256) void scanC_mfma(const bf16_t* __restrict__ xBCb,
                                                  const float* __restrict__ dt,
                                                  const float* __restrict__ ldA,
                                                  const bf16_t* __restrict__ Sini,
                                                  const float* __restrict__ Dskip,
                                                  float* __restrict__ ybuf) {
    int bid = blockIdx.x;
    int ph = bid & 1, c = (bid >> 1) & 31, hd = (bid >> 6) & 7, b = bid >> 9;
    int t = threadIdx.x, wave = t >> 6, lane = t & 63;
    int lr = lane & 15, quad = lane >> 4;
    int pb = ph * 64;
    __shared__ bf16_t XT[64*LDT];    // [p-half][t]
    __shared__ bf16_t Mlds[64*LDT];  // [t][s]
    __shared__ float Ls[CHUNK], dts[CHUNK];
    int m0tok = b*SEQ + c*CHUNK;
    int bhc = (b*NHEADS + hd)*NCHUNK + c;
    if (t < 64) {
        float L = ldA[(m0tok + t)*NHEADS + hd];
#pragma unroll
        for (int d = 1; d < 64; d <<= 1) {
            float u = __shfl_up(L, d, 64);
            if (lane >= d) L += u;
        }
        Ls[t] = L;
        dts[t] = dt[(m0tok + t)*NHEADS + hd];
    }
    int tt = t & 63;
#pragma unroll
    for (int i = 0; i < 2; i++) {
        int pg = i*4 + (t >> 6);
        short8 xv = *(const short8*)(xBCb + (size_t)(m0tok + tt)*CONVDIM + hd*HEADDIM + pb + pg*8);
#pragma unroll
        for (int j = 0; j < 8; j++) {
            short sv = xv[j];
            XT[(pg*8 + j)*LDT + tt] = *(bf16_t*)&sv;
        }
    }
    __syncthreads();
    const bf16_t* Crow = xBCb + (size_t)m0tok*CONVDIM + DINNER + DSTATE;
    const bf16_t* Brow = xBCb + (size_t)m0tok*CONVDIM + DINNER;
    // --- G = C @ B^T for t-rows [wave*16, wave*16+16) (duplicated across p-halves) ---
    f32x4 g[4];
#pragma unroll
    for (int si = 0; si < 4; si++) g[si] = (f32x4){0.f,0.f,0.f,0.f};
#pragma unroll
    for (int k0 = 0; k0 < 128; k0 += 32) {
        short8 a = *(const short8*)(Crow + (size_t)(wave*16 + lr)*CONVDIM + k0 + quad*8);
#pragma unroll
        for (int si = 0; si < 4; si++) {
            short8 bb = *(const short8*)(Brow + (size_t)(si*16 + lr)*CONVDIM + k0 + quad*8);
            g[si] = __builtin_amdgcn_mfma_f32_16x16x32_bf16(a, bb, g[si], 0, 0, 0);
        }
    }
#pragma unroll
    for (int si = 0; si < 4; si++)
#pragma unroll
        for (int r = 0; r < 4; r++) {
            int tr = wave*16 + quad*4 + r;
            int ss = si*16 + lr;
            float v = (ss <= tr) ? g[si][r] * expf(Ls[tr] - Ls[ss]) * dts[ss] : 0.f;
            Mlds[tr*LDT + ss] = __float2bfloat16(v);
        }
    __syncthreads();
    // --- Y: wave handles p-cols [pb + wave*16, +16) ---
    int pw = wave * 16;
    f32x4 acc[4];
#pragma unroll
    for (int mi = 0; mi < 4; mi++) acc[mi] = (f32x4){0.f,0.f,0.f,0.f};
    const bf16_t* Sb = Sini + (size_t)bhc * 16384;
#pragma unroll
    for (int k0 = 0; k0 < 128; k0 += 32) {
        short8 aC[4];
#pragma unroll
        for (int mi = 0; mi < 4; mi++)
            aC[mi] = *(const short8*)(Crow + (size_t)(mi*16 + lr)*CONVDIM + k0 + quad*8);
        short8 bb = *(const short8*)(Sb + (size_t)(pb + pw + lr)*128 + k0 + quad*8);
#pragma unroll
        for (int mi = 0; mi < 4; mi++)
            acc[mi] = __builtin_amdgcn_mfma_f32_16x16x32_bf16(aC[mi], bb, acc[mi], 0, 0, 0);
    }
#pragma unroll
    for (int mi = 0; mi < 4; mi++) {
#pragma unroll
        for (int r = 0; r < 4; r++) acc[mi][r] *= expf(Ls[mi*16 + quad*4 + r]);
    }
#pragma unroll
    for (int k0 = 0; k0 < 64; k0 += 32) {
        short8 aM[4];
#pragma unroll
        for (int mi = 0; mi < 4; mi++)
            aM[mi] = *(const short8*)&Mlds[(mi*16 + lr)*LDT + k0 + quad*8];
        short8 bb = *(const short8*)&XT[(pw + lr)*LDT + k0 + quad*8];
#pragma unroll
        for (int mi = 0; mi < 4; mi++)
            acc[mi] = __builtin_amdgcn_mfma_f32_16x16x32_bf16(aM[mi], bb, acc[mi], 0, 0, 0);
    }
    float dsk = Dskip[hd];
#pragma unroll
    for (int mi = 0; mi < 4; mi++)
#pragma unroll
        for (int r = 0; r < 4; r++) {
            int tr = mi*16 + quad*4 + r;
            int pl = pw + lr;
            float xv = bf2f(*(const short*)&XT[pl*LDT + tr]);
            int m = m0tok + tr;
            ybuf[(size_t)m*DINNER + hd*HEADDIM + pb + pl] = acc[mi][r] + dsk*xv;
        }
}

// ---- fused gate(silu(z)) + RMSNorm + out_proj + residual + LN2 + MLP; 512 threads ----
__global__ __launch_bounds__(512) void gate_out_mlp(const float* __restrict__ ybuf,
                                                    const bf16_t* __restrict__ zbuf,
                                                    const float* __restrict__ gw,
                                                    const bf16_t* __restrict__ Wb,
                                                    const float* __restrict__ resid,
                                                    const float* __restrict__ w2,
                                                    const float* __restrict__ b2,
                                                    const bf16_t* __restrict__ Wm,
                                                    const float* __restrict__ mb,
                                                    float* __restrict__ out) {
    int blk = blockIdx.x, t = threadIdx.x;
    int tok0 = blk * 16;
    int wave = t >> 6, lane = t & 63, lr = lane & 15, quad = lane >> 4;
    __shared__ bf16_t A[16*1032];
    __shared__ float mixs[16*132];
    // phase 1: gate + RMSNorm. 32 threads per token, 32 channels each.
    int tt = t >> 5, cg = t & 31;
    int ch0 = cg * 32;
    float vals[32];
    const float*  yr = ybuf + (size_t)(tok0 + tt)*DINNER + ch0;
    const bf16_t* zr = zbuf + (size_t)(tok0 + tt)*DINNER + ch0;
    float ss = 0.f;
#pragma unroll
    for (int i = 0; i < 32; i += 4) {
        f32x4 y = *(const f32x4*)(yr + i);
        short4v z = *(const short4v*)(zr + i);
#pragma unroll
        for (int r = 0; r < 4; r++) {
            float v = y[r] * silu_f(bf2f(z[r]));
            vals[i + r] = v; ss += v*v;
        }
    }
#pragma unroll
    for (int d = 1; d < 32; d <<= 1) ss += __shfl_xor(ss, d, 64);
    float rstd = rsqrtf(ss*(1.f/1024.f) + 1e-5f);
#pragma unroll
    for (int i = 0; i < 32; i += 4) {
        short4v pk;
#pragma unroll
        for (int r = 0; r < 4; r++) pk[r] = f2bf_s(vals[i+r]*rstd*gw[ch0+i+r]);
        *(short4v*)&A[tt*1032 + ch0 + i] = pk;
    }
    __syncthreads();
    // phase 2: out_proj GEMM. 8 waves x 16 cols.
    int col = wave*16 + lr;
    f32x4 acc = (f32x4){0.f,0.f,0.f,0.f};
    for (int k0 = 0; k0 < 1024; k0 += 32) {
        short8 a = *(const short8*)&A[lr*1032 + k0 + quad*8];
        short8 bb = *(const short8*)(Wb + (size_t)col*DINNER + k0 + quad*8);
        acc = __builtin_amdgcn_mfma_f32_16x16x32_bf16(a, bb, acc, 0, 0, 0);
    }
#pragma unroll
    for (int r = 0; r < 4; r++)
        mixs[(quad*4 + r)*132 + col] = acc[r];
    __syncthreads();
    // phase 3: residual + LN2. 32 threads per token, 4 channels each.
    int ch4 = (t & 31) * 4;
    const float* rr = resid + (size_t)(tok0 + tt)*DMODEL + ch4;
    f32x4 r0 = *(const f32x4*)rr;
    float v2[4];
#pragma unroll
    for (int r = 0; r < 4; r++) v2[r] = mixs[tt*132 + ch4 + r] + r0[r];
    float s2 = 0.f, sq = 0.f;
#pragma unroll
    for (int i = 0; i < 4; i++) { s2 += v2[i]; sq += v2[i]*v2[i]; }
#pragma unroll
    for (int d = 1; d < 32; d <<= 1) { s2 += __shfl_xor(s2, d, 64); sq += __shfl_xor(sq, d, 64); }
    float mean = s2 * (1.f/128.f);
    float var  = sq * (1.f/128.f) - mean*mean;
    float rstd2 = rsqrtf(var + 1e-5f);
    {
        short4v p0;
#pragma unroll
        for (int r = 0; r < 4; r++)
            p0[r] = f2bf_s((v2[r] - mean)*rstd2*w2[ch4+r] + b2[ch4+r]);
        *(short4v*)&A[tt*136 + ch4] = p0;   // reuse A storage (phase-2 reads done)
    }
    __syncthreads();
    // phase 4: MLP GEMM. 8 waves x 16 cols.
    f32x4 acc2 = (f32x4){0.f,0.f,0.f,0.f};
#pragma unroll
    for (int k0 = 0; k0 < 128; k0 += 32) {
        short8 a = *(const short8*)&A[lr*136 + k0 + quad*8];
        short8 bb = *(const short8*)(Wm + (size_t)col*DMODEL + k0 + quad*8);
        acc2 = __builtin_amdgcn_mfma_f32_16x16x32_bf16(a, bb, acc2, 0, 0, 0);
    }
#pragma unroll
    for (int r = 0; r < 4; r++)
        out[(size_t)(tok0 + quad*4 + r)*DMODEL + col] = acc2[r] + mb[col];
}

extern "C" void kernel_launch(void* const* d_in, const int* in_sizes, int n_in,
                              void* d_out, int out_size, void* d_ws, size_t ws_size,
                              hipStream_t stream) {
    const float* hidden  = (const float*)d_in[0];
    const float* w_in    = (const float*)d_in[1];
    const float* conv_w  = (const float*)d_in[2];
    const float* conv_b  = (const float*)d_in[3];
    const float* dt_bias = (const float*)d_in[4];
    const float* A_log   = (const float*)d_in[5];
    const float* D_skip  = (const float*)d_in[6];
    const float* gnorm_w = (const float*)d_in[7];
    const float* w_out   = (const float*)d_in[8];
    const float* ln1_w   = (const float*)d_in[9];
    const float* ln1_b   = (const float*)d_in[10];
    const float* ln2_w   = (const float*)d_in[11];
    const float* ln2_b   = (const float*)d_in[12];
    const float* mlp_w   = (const float*)d_in[13];
    const float* mlp_b   = (const float*)d_in[14];
    float* out = (float*)d_out;

    char* ws = (char*)d_ws;
    size_t off = 0;
    auto alloc = [&](size_t bytes) -> void* {
        void* p = ws + off;
        off = (off + bytes + 255) & ~(size_t)255;
        return p;
    };
    bf16_t* h_bf   = (bf16_t*)alloc((size_t)NTOK*DMODEL*2);
    bf16_t* w_in_bf= (bf16_t*)alloc((size_t)NPROJ*DMODEL*2);
    bf16_t* w_out_bf=(bf16_t*)alloc((size_t)DMODEL*DINNER*2);
    bf16_t* mlp_bf = (bf16_t*)alloc((size_t)DMODEL*DMODEL*2);
    bf16_t* zbuf   = (bf16_t*)alloc((size_t)NTOK*DINNER*2);
    bf16_t* xBCb   = (bf16_t*)alloc((size_t)NTOK*CONVDIM*2);
    float*  dtb    = (float*) alloc((size_t)NTOK*NHEADS*4);
    float*  ldAb   = (float*) alloc((size_t)NTOK*NHEADS*4);
    bf16_t* Sloc   = (bf16_t*)alloc((size_t)B_SZ*NHEADS*NCHUNK*16384*2);
    bf16_t* Sini   = (bf16_t*)alloc((size_t)B_SZ*NHEADS*NCHUNK*16384*2);
    float*  Pbuf   = (float*) alloc((size_t)B_SZ*NHEADS*NCHUNK*4);
    float*  ybuf   = (float*) alloc((size_t)NTOK*DINNER*4);
    (void)ws_size; (void)in_sizes; (void)n_in; (void)out_size;

    // fused: weight casts + LN1 + dt head
    {
        int na = NPROJ*DMODEL, nb = DMODEL*DINNER, nc = DMODEL*DMODEL;
        int castBlocks = (na + nb + nc) / 4 / 128;   // exact: 442368/512 = 864
        head_fused<<<NTOK + castBlocks, 128, 0, stream>>>(
            hidden, ln1_w, ln1_b, w_in, dt_bias, A_log, h_bf, dtb, ldAb,
            w_in, na, w_out, nb, mlp_w, nc, w_in_bf, w_out_bf, mlp_bf);
    }
    // in_proj GEMM with fused conv+silu (z -> zbuf; xBC -> conv -> xBCb)
    gemm_conv<<<dim3(64, 36), 256, 0, stream>>>(h_bf, w_in_bf, conv_w, conv_b, zbuf, xBCb);
    // chunked scan (SSD, MFMA); SSA dataflow Sloc -> Sini
    scanA_mfma<<<1024, 256, 0, stream>>>(xBCb, dtb, ldAb, Sloc, Pbuf);
    scanB<<<512, 256, 0, stream>>>(Sloc, Sini, Pbuf);
    scanC_mfma<<<1024, 256, 0, stream>>>(xBCb, dtb, ldAb, Sini, D_skip, ybuf);
    // fused gate + RMSNorm + out_proj + residual + LN2 + MLP
    gate_out_mlp<<<NTOK/16, 512, 0, stream>>>(ybuf, zbuf, gnorm_w, w_out_bf,
                                              hidden, ln2_w, ln2_b, mlp_bf, mlp_b, out);
}